// Round 1
// baseline (59.029 us; speedup 1.0000x reference)
//
#include <hip/hip_runtime.h>

#define N 1536

// ---------------- K1: node encoder + message projection ----------------
// h = relu(relu(x@W1+b1)@W2+b2)   [N,64]
// p = h@Wm                        [N,64]
// 4 rows per block (one per wave), lane c owns channel c.
__global__ __launch_bounds__(256) void enc_kernel(
    const float* __restrict__ x, const float* __restrict__ W1, const float* __restrict__ b1,
    const float* __restrict__ W2, const float* __restrict__ b2,
    const float* __restrict__ Wm,
    float* __restrict__ h, float* __restrict__ p)
{
    __shared__ float sW2[64 * 64];
    __shared__ float sWm[64 * 64];
    __shared__ float buf1[4][64];
    __shared__ float buf2[4][64];
    int t = threadIdx.x;
    int w = t >> 6, c = t & 63;
    int row = blockIdx.x * 4 + w;

    #pragma unroll
    for (int i = t; i < 64 * 64; i += 256) { sW2[i] = W2[i]; sWm[i] = Wm[i]; }

    float x0 = x[row * 4 + 0], x1 = x[row * 4 + 1];
    float x2 = x[row * 4 + 2], x3 = x[row * 4 + 3];
    float h1 = x0 * W1[0 * 64 + c] + x1 * W1[1 * 64 + c]
             + x2 * W1[2 * 64 + c] + x3 * W1[3 * 64 + c] + b1[c];
    h1 = fmaxf(0.f, h1);
    buf1[w][c] = h1;
    __syncthreads();               // sW2/sWm staged; buf1 visible

    float h2 = b2[c];
    #pragma unroll
    for (int k = 0; k < 64; ++k) h2 = fmaf(buf1[w][k], sW2[k * 64 + c], h2);
    h2 = fmaxf(0.f, h2);
    h[row * 64 + c] = h2;
    buf2[w][c] = h2;               // per-wave buffer, in-wave RAW handled by lgkmcnt
    __syncthreads();

    float pv = 0.f;
    #pragma unroll
    for (int k = 0; k < 64; ++k) pv = fmaf(buf2[w][k], sWm[k * 64 + c], pv);
    p[row * 64 + c] = pv;
}

// ---------------- K2: message pass (the N^2 part) ----------------
// msgs[i,c] = (1/N) * sum_j relu(p[j,c] - (p[i,c] - bm[c]))
// Block: 256 threads = 4 j-groups x 64 channels; 4 i-rows per block.
__global__ __launch_bounds__(256) void msg_kernel(
    const float* __restrict__ p, const float* __restrict__ bm,
    float* __restrict__ msgs)
{
    int t = threadIdx.x;
    int c = t & 63, g = t >> 6;
    int i0 = blockIdx.x * 4;

    float bmc = bm[c];
    float q0 = p[(i0 + 0) * 64 + c] - bmc;
    float q1 = p[(i0 + 1) * 64 + c] - bmc;
    float q2 = p[(i0 + 2) * 64 + c] - bmc;
    float q3 = p[(i0 + 3) * 64 + c] - bmc;

    float a0 = 0.f, a1 = 0.f, a2 = 0.f, a3 = 0.f;
    #pragma unroll 4
    for (int j = g; j < N; j += 4) {
        float pj = p[j * 64 + c];
        a0 += fmaxf(0.f, pj - q0);
        a1 += fmaxf(0.f, pj - q1);
        a2 += fmaxf(0.f, pj - q2);
        a3 += fmaxf(0.f, pj - q3);
    }

    __shared__ float red[4][4][64];
    red[g][0][c] = a0; red[g][1][c] = a1; red[g][2][c] = a2; red[g][3][c] = a3;
    __syncthreads();
    // thread of group g finalizes row i0+g
    float s = red[0][g][c] + red[1][g][c] + red[2][g][c] + red[3][g][c];
    msgs[(i0 + g) * 64 + c] = s * (1.0f / N);
}

// ---------------- K3: update MLP + heads ----------------
// hu = [h, msgs]; u = relu(relu(hu@Wu1+bu1)@Wu2+bu2)
// out: mean = u@Wmean+bmean -> out[0..3071]; std=exp(log_std) -> out[3072..3073];
//      v = u@Wv+bv -> out[3074..4609]
#define R 8
__global__ __launch_bounds__(128) void upd_kernel(
    const float* __restrict__ h, const float* __restrict__ msgs,
    const float* __restrict__ Wu1, const float* __restrict__ bu1,
    const float* __restrict__ Wu2, const float* __restrict__ bu2,
    const float* __restrict__ Wmean, const float* __restrict__ bmean,
    const float* __restrict__ Wv, const float* __restrict__ bv,
    const float* __restrict__ log_std,
    float* __restrict__ out)
{
    int t = threadIdx.x;        // 0..127, channel
    int r0 = blockIdx.x * R;

    __shared__ float hu[R][128];
    __shared__ float u1s[R][128];

    #pragma unroll
    for (int r = 0; r < R; ++r) {
        int row = r0 + r;
        hu[r][t] = (t < 64) ? h[row * 64 + t] : msgs[row * 64 + (t - 64)];
    }
    __syncthreads();

    float u1[R];
    #pragma unroll
    for (int r = 0; r < R; ++r) u1[r] = bu1[t];
    for (int k = 0; k < 128; ++k) {
        float w = Wu1[k * 128 + t];
        #pragma unroll
        for (int r = 0; r < R; ++r) u1[r] = fmaf(hu[r][k], w, u1[r]);   // hu[r][k] is a broadcast
    }
    #pragma unroll
    for (int r = 0; r < R; ++r) u1s[r][t] = fmaxf(0.f, u1[r]);
    __syncthreads();

    float u2[R];
    #pragma unroll
    for (int r = 0; r < R; ++r) u2[r] = bu2[t];
    for (int k = 0; k < 128; ++k) {
        float w = Wu2[k * 128 + t];
        #pragma unroll
        for (int r = 0; r < R; ++r) u2[r] = fmaf(u1s[r][k], w, u2[r]);
    }
    __syncthreads();            // before reusing hu
    #pragma unroll
    for (int r = 0; r < R; ++r) hu[r][t] = fmaxf(0.f, u2[r]);
    __syncthreads();

    // heads: 3 dot products per row, 24 worker threads
    if (t < R * 3) {
        int r = t / 3, o = t % 3;
        int row = r0 + r;
        float acc = 0.f;
        if (o < 2) {
            for (int k = 0; k < 128; ++k) acc += hu[r][k] * Wmean[k * 2 + o];
            out[row * 2 + o] = acc + bmean[o];
        } else {
            for (int k = 0; k < 128; ++k) acc += hu[r][k] * Wv[k];
            out[3074 + row] = acc + bv[0];
        }
    }
    if (blockIdx.x == 0 && t < 2) {
        out[3072 + t] = expf(log_std[t]);
    }
}

extern "C" void kernel_launch(void* const* d_in, const int* in_sizes, int n_in,
                              void* d_out, int out_size, void* d_ws, size_t ws_size,
                              hipStream_t stream) {
    const float* x      = (const float*)d_in[0];
    const float* W1     = (const float*)d_in[1];
    const float* b1     = (const float*)d_in[2];
    const float* W2     = (const float*)d_in[3];
    const float* b2     = (const float*)d_in[4];
    const float* Wm     = (const float*)d_in[5];
    const float* bm     = (const float*)d_in[6];
    const float* Wu1    = (const float*)d_in[7];
    const float* bu1    = (const float*)d_in[8];
    const float* Wu2    = (const float*)d_in[9];
    const float* bu2    = (const float*)d_in[10];
    const float* Wmean  = (const float*)d_in[11];
    const float* bmean  = (const float*)d_in[12];
    const float* Wv     = (const float*)d_in[13];
    const float* bv     = (const float*)d_in[14];
    const float* log_std= (const float*)d_in[15];
    float* out = (float*)d_out;

    float* ws   = (float*)d_ws;
    float* h    = ws;              // N*64
    float* p    = ws + N * 64;     // N*64
    float* msgs = ws + 2 * N * 64; // N*64

    enc_kernel<<<N / 4, 256, 0, stream>>>(x, W1, b1, W2, b2, Wm, h, p);
    msg_kernel<<<N / 4, 256, 0, stream>>>(p, bm, msgs);
    upd_kernel<<<N / R, 128, 0, stream>>>(h, msgs, Wu1, bu1, Wu2, bu2,
                                          Wmean, bmean, Wv, bv, log_std, out);
}

// Round 2
// 49.198 us; speedup vs baseline: 1.1998x; 1.1998x over previous
//
#include <hip/hip_runtime.h>

#define N 1536

// ---------------- K1: node encoder + message projection ----------------
// h = relu(relu(x@W1+b1)@W2+b2)   [N,64]
// p = h@Wm                        [N,64]
// 4 rows per block (one per wave), lane c owns channel c.
__global__ __launch_bounds__(256) void enc_kernel(
    const float* __restrict__ x, const float* __restrict__ W1, const float* __restrict__ b1,
    const float* __restrict__ W2, const float* __restrict__ b2,
    const float* __restrict__ Wm,
    float* __restrict__ h, float* __restrict__ p)
{
    __shared__ float sW2[64 * 64];
    __shared__ float sWm[64 * 64];
    __shared__ float buf1[4][64];
    __shared__ float buf2[4][64];
    int t = threadIdx.x;
    int w = t >> 6, c = t & 63;
    int row = blockIdx.x * 4 + w;

    #pragma unroll
    for (int i = t; i < 64 * 64; i += 256) { sW2[i] = W2[i]; sWm[i] = Wm[i]; }

    float x0 = x[row * 4 + 0], x1 = x[row * 4 + 1];
    float x2 = x[row * 4 + 2], x3 = x[row * 4 + 3];
    float h1 = x0 * W1[0 * 64 + c] + x1 * W1[1 * 64 + c]
             + x2 * W1[2 * 64 + c] + x3 * W1[3 * 64 + c] + b1[c];
    h1 = fmaxf(0.f, h1);
    buf1[w][c] = h1;
    __syncthreads();               // sW2/sWm staged; buf1 visible

    float h2 = b2[c];
    #pragma unroll
    for (int k = 0; k < 64; ++k) h2 = fmaf(buf1[w][k], sW2[k * 64 + c], h2);
    h2 = fmaxf(0.f, h2);
    h[row * 64 + c] = h2;
    buf2[w][c] = h2;
    __syncthreads();

    float pv = 0.f;
    #pragma unroll
    for (int k = 0; k < 64; ++k) pv = fmaf(buf2[w][k], sWm[k * 64 + c], pv);
    p[row * 64 + c] = pv;
}

// ---------------- K2: fused message pass + update MLP + heads ----------------
// msgs[i,c] = (1/N) * sum_j relu(p[j,c] - (p[i,c] - bm[c]))
// hu = [h, msgs]; u = relu(relu(hu@Wu1+bu1)@Wu2+bu2)
// out[0..3071] = u@Wmean+bmean; out[3072..3073] = exp(log_std); out[3074..4609] = u@Wv+bv
#define RI 8     // rows per block
#define G  8     // j-groups (waves)
__global__ __launch_bounds__(512) void msg_upd_kernel(
    const float* __restrict__ p, const float* __restrict__ bm,
    const float* __restrict__ h,
    const float* __restrict__ Wu1, const float* __restrict__ bu1,
    const float* __restrict__ Wu2, const float* __restrict__ bu2,
    const float* __restrict__ Wmean, const float* __restrict__ bmean,
    const float* __restrict__ Wv, const float* __restrict__ bv,
    const float* __restrict__ log_std,
    float* __restrict__ out)
{
    __shared__ float red[G][RI][64];     // 16 KB  (j-group partials)
    __shared__ float hu[RI][128];        // 4 KB   ([h, msgs] then reused for u2)
    __shared__ float u1s[RI][128];       // 4 KB
    __shared__ float part[4][RI][128];   // 16 KB  (k-split partials)

    int t = threadIdx.x;
    int c = t & 63, g = t >> 6;          // g in 0..7 (wave id)
    int i0 = blockIdx.x * RI;

    // ---- phase A: message pass for rows i0..i0+7 ----
    float bmc = bm[c];
    float q[RI];
    #pragma unroll
    for (int r = 0; r < RI; ++r) q[r] = p[(i0 + r) * 64 + c] - bmc;

    float acc[RI];
    #pragma unroll
    for (int r = 0; r < RI; ++r) acc[r] = 0.f;

    // 192 j's per group, unroll 2 for load batching (1536 / 16 = 96 iters)
    for (int j = g; j < N; j += 2 * G) {
        float pj0 = p[j * 64 + c];
        float pj1 = p[(j + G) * 64 + c];
        #pragma unroll
        for (int r = 0; r < RI; ++r) {
            acc[r] += fmaxf(0.f, pj0 - q[r]);
            acc[r] += fmaxf(0.f, pj1 - q[r]);
        }
    }
    #pragma unroll
    for (int r = 0; r < RI; ++r) red[g][r][c] = acc[r];

    // stage h rows into hu[:, 0:64] (RI == G == 8, so (g,c) covers all 8x64)
    hu[g][c] = h[(i0 + g) * 64 + c];
    __syncthreads();

    // reduce 8 j-group partials; thread (g,c) owns row g, channel c
    {
        float s = 0.f;
        #pragma unroll
        for (int gg = 0; gg < G; ++gg) s += red[gg][g][c];
        hu[g][64 + c] = s * (1.0f / N);
    }
    __syncthreads();

    // ---- phase B: update MLP, k split across 4 thread groups ----
    int ch = t & 127, kh = t >> 7;       // kh in 0..3, k-range [kh*32, kh*32+32)
    {
        float u1[RI];
        #pragma unroll
        for (int r = 0; r < RI; ++r) u1[r] = 0.f;
        #pragma unroll 8
        for (int k = kh * 32; k < kh * 32 + 32; ++k) {
            float w = Wu1[k * 128 + ch];
            #pragma unroll
            for (int r = 0; r < RI; ++r) u1[r] = fmaf(hu[r][k], w, u1[r]);
        }
        #pragma unroll
        for (int r = 0; r < RI; ++r) part[kh][r][ch] = u1[r];
    }
    __syncthreads();
    {   // reduce + bias + relu; thread (kh,ch) owns rows kh*2, kh*2+1
        float bias = bu1[ch];
        #pragma unroll
        for (int rr = kh * 2; rr < kh * 2 + 2; ++rr) {
            float v = part[0][rr][ch] + part[1][rr][ch]
                    + part[2][rr][ch] + part[3][rr][ch] + bias;
            u1s[rr][ch] = fmaxf(0.f, v);
        }
    }
    __syncthreads();
    {
        float u2[RI];
        #pragma unroll
        for (int r = 0; r < RI; ++r) u2[r] = 0.f;
        #pragma unroll 8
        for (int k = kh * 32; k < kh * 32 + 32; ++k) {
            float w = Wu2[k * 128 + ch];
            #pragma unroll
            for (int r = 0; r < RI; ++r) u2[r] = fmaf(u1s[r][k], w, u2[r]);
        }
        #pragma unroll
        for (int r = 0; r < RI; ++r) part[kh][r][ch] = u2[r];
    }
    __syncthreads();
    {   // reduce + bias + relu -> final u into hu[r][ch]
        float bias = bu2[ch];
        #pragma unroll
        for (int rr = kh * 2; rr < kh * 2 + 2; ++rr) {
            float v = part[0][rr][ch] + part[1][rr][ch]
                    + part[2][rr][ch] + part[3][rr][ch] + bias;
            hu[rr][ch] = fmaxf(0.f, v);
        }
    }
    __syncthreads();

    // ---- heads: row r = g, 64-lane shuffle reduction per row ----
    {
        int r = g, lane = c;
        float a  = hu[r][lane];
        float b2 = hu[r][lane + 64];
        float m0 = a * Wmean[lane * 2 + 0] + b2 * Wmean[(lane + 64) * 2 + 0];
        float m1 = a * Wmean[lane * 2 + 1] + b2 * Wmean[(lane + 64) * 2 + 1];
        float vv = a * Wv[lane]            + b2 * Wv[lane + 64];
        #pragma unroll
        for (int off = 32; off > 0; off >>= 1) {
            m0 += __shfl_down(m0, off);
            m1 += __shfl_down(m1, off);
            vv += __shfl_down(vv, off);
        }
        if (lane == 0) {
            int row = i0 + r;
            out[row * 2 + 0] = m0 + bmean[0];
            out[row * 2 + 1] = m1 + bmean[1];
            out[3074 + row]  = vv + bv[0];
        }
    }
    if (blockIdx.x == 0 && t < 2) {
        out[3072 + t] = expf(log_std[t]);
    }
}

extern "C" void kernel_launch(void* const* d_in, const int* in_sizes, int n_in,
                              void* d_out, int out_size, void* d_ws, size_t ws_size,
                              hipStream_t stream) {
    const float* x      = (const float*)d_in[0];
    const float* W1     = (const float*)d_in[1];
    const float* b1     = (const float*)d_in[2];
    const float* W2     = (const float*)d_in[3];
    const float* b2     = (const float*)d_in[4];
    const float* Wm     = (const float*)d_in[5];
    const float* bm     = (const float*)d_in[6];
    const float* Wu1    = (const float*)d_in[7];
    const float* bu1    = (const float*)d_in[8];
    const float* Wu2    = (const float*)d_in[9];
    const float* bu2    = (const float*)d_in[10];
    const float* Wmean  = (const float*)d_in[11];
    const float* bmean  = (const float*)d_in[12];
    const float* Wv     = (const float*)d_in[13];
    const float* bv     = (const float*)d_in[14];
    const float* log_std= (const float*)d_in[15];
    float* out = (float*)d_out;

    float* ws = (float*)d_ws;
    float* h  = ws;              // N*64
    float* p  = ws + N * 64;     // N*64

    enc_kernel<<<N / 4, 256, 0, stream>>>(x, W1, b1, W2, b2, Wm, h, p);
    msg_upd_kernel<<<N / RI, 512, 0, stream>>>(p, bm, h, Wu1, bu1, Wu2, bu2,
                                               Wmean, bmean, Wv, bv, log_std, out);
}

// Round 3
// 26.777 us; speedup vs baseline: 2.2045x; 1.8373x over previous
//
#include <hip/hip_runtime.h>

#define N 1536

// ---------------- K1: node encoder + message projection ----------------
__global__ __launch_bounds__(256) void enc_kernel(
    const float* __restrict__ x, const float* __restrict__ W1, const float* __restrict__ b1,
    const float* __restrict__ W2, const float* __restrict__ b2,
    const float* __restrict__ Wm,
    float* __restrict__ h, float* __restrict__ p)
{
    __shared__ float sW2[64 * 64];
    __shared__ float sWm[64 * 64];
    __shared__ float buf1[4][64];
    __shared__ float buf2[4][64];
    int t = threadIdx.x;
    int w = t >> 6, c = t & 63;
    int row = blockIdx.x * 4 + w;

    #pragma unroll
    for (int i = t; i < 64 * 64; i += 256) { sW2[i] = W2[i]; sWm[i] = Wm[i]; }

    float x0 = x[row * 4 + 0], x1 = x[row * 4 + 1];
    float x2 = x[row * 4 + 2], x3 = x[row * 4 + 3];
    float h1 = x0 * W1[0 * 64 + c] + x1 * W1[1 * 64 + c]
             + x2 * W1[2 * 64 + c] + x3 * W1[3 * 64 + c] + b1[c];
    h1 = fmaxf(0.f, h1);
    buf1[w][c] = h1;
    __syncthreads();

    float h2 = b2[c];
    #pragma unroll
    for (int k = 0; k < 64; ++k) h2 = fmaf(buf1[w][k], sW2[k * 64 + c], h2);
    h2 = fmaxf(0.f, h2);
    h[row * 64 + c] = h2;
    buf2[w][c] = h2;
    __syncthreads();

    float pv = 0.f;
    #pragma unroll
    for (int k = 0; k < 64; ++k) pv = fmaf(buf2[w][k], sWm[k * 64 + c], pv);
    p[row * 64 + c] = pv;
}

// ---------------- K2: fused message pass + update MLP + heads ----------------
// 256 blocks x 1024 threads (16 waves = 4/SIMD). RI=6 rows per block.
#define RI 6     // rows per block  (256 * 6 = 1536)
#define G  16    // j-groups (one per wave)
#define JB 8     // load batch depth
__global__ __launch_bounds__(1024) void msg_upd_kernel(
    const float* __restrict__ p, const float* __restrict__ bm,
    const float* __restrict__ h,
    const float* __restrict__ Wu1, const float* __restrict__ bu1,
    const float* __restrict__ Wu2, const float* __restrict__ bu2,
    const float* __restrict__ Wmean, const float* __restrict__ bmean,
    const float* __restrict__ Wv, const float* __restrict__ bv,
    const float* __restrict__ log_std,
    float* __restrict__ out)
{
    __shared__ float red[G][RI][64];     // 24 KB  (j-group partials)
    __shared__ float hu[RI][128];        // 3 KB   ([h, msgs], reused for final u)
    __shared__ float u1s[RI][128];       // 3 KB
    __shared__ float part[8][RI][128];   // 24 KB  (k-split partials)

    int t = threadIdx.x;
    int c = t & 63, g = t >> 6;          // g in 0..15 (wave id)
    int i0 = blockIdx.x * RI;

    // ---- phase A: message pass for rows i0..i0+RI-1 ----
    float bmc = bm[c];
    float q[RI];
    #pragma unroll
    for (int r = 0; r < RI; ++r) q[r] = p[(i0 + r) * 64 + c] - bmc;

    float acc[RI];
    #pragma unroll
    for (int r = 0; r < RI; ++r) acc[r] = 0.f;

    // 96 j's per thread, batched 8 deep: 12 groups of 8 loads in flight
    for (int jj = 0; jj < N / G; jj += JB) {
        float pj[JB];
        #pragma unroll
        for (int u = 0; u < JB; ++u) pj[u] = p[(g + (jj + u) * G) * 64 + c];
        #pragma unroll
        for (int u = 0; u < JB; ++u) {
            #pragma unroll
            for (int r = 0; r < RI; ++r) acc[r] += fmaxf(0.f, pj[u] - q[r]);
        }
    }
    #pragma unroll
    for (int r = 0; r < RI; ++r) red[g][r][c] = acc[r];

    // concurrently stage h rows into hu[:, 0:64] (384 entries)
    if (t >= 512 && t < 512 + RI * 64) {
        int tt = t - 512;
        hu[tt >> 6][tt & 63] = h[(i0 + (tt >> 6)) * 64 + (tt & 63)];
    }
    __syncthreads();

    // reduce 16 j-group partials; threads t<RI*64: (r, c)
    if (t < RI * 64) {
        int r = t >> 6, cc = t & 63;
        float s = 0.f;
        #pragma unroll
        for (int gg = 0; gg < G; ++gg) s += red[gg][r][cc];
        hu[r][64 + cc] = s * (1.0f / N);
    }
    __syncthreads();

    // ---- phase B: update MLP, k split across 8 thread groups of 16 ----
    int ch = t & 127, kh = t >> 7;       // kh in 0..7, k-range [kh*16, kh*16+16)
    {
        float u1[RI];
        #pragma unroll
        for (int r = 0; r < RI; ++r) u1[r] = 0.f;
        #pragma unroll
        for (int k = kh * 16; k < kh * 16 + 16; ++k) {
            float w = Wu1[k * 128 + ch];
            #pragma unroll
            for (int r = 0; r < RI; ++r) u1[r] = fmaf(hu[r][k], w, u1[r]);
        }
        #pragma unroll
        for (int r = 0; r < RI; ++r) part[kh][r][ch] = u1[r];
    }
    __syncthreads();
    if (t < RI * 128) {   // reduce + bias + relu
        int r = t >> 7, cc = t & 127;
        float v = bu1[cc];
        #pragma unroll
        for (int kk = 0; kk < 8; ++kk) v += part[kk][r][cc];
        u1s[r][cc] = fmaxf(0.f, v);
    }
    __syncthreads();
    {
        float u2[RI];
        #pragma unroll
        for (int r = 0; r < RI; ++r) u2[r] = 0.f;
        #pragma unroll
        for (int k = kh * 16; k < kh * 16 + 16; ++k) {
            float w = Wu2[k * 128 + ch];
            #pragma unroll
            for (int r = 0; r < RI; ++r) u2[r] = fmaf(u1s[r][k], w, u2[r]);
        }
        #pragma unroll
        for (int r = 0; r < RI; ++r) part[kh][r][ch] = u2[r];
    }
    __syncthreads();
    if (t < RI * 128) {   // reduce + bias + relu -> final u into hu
        int r = t >> 7, cc = t & 127;
        float v = bu2[cc];
        #pragma unroll
        for (int kk = 0; kk < 8; ++kk) v += part[kk][r][cc];
        hu[r][cc] = fmaxf(0.f, v);
    }
    __syncthreads();

    // ---- heads: wave w < RI handles row w, 64-lane shuffle reduction ----
    if (g < RI) {
        int r = g, lane = c;
        float a  = hu[r][lane];
        float b2 = hu[r][lane + 64];
        float m0 = a * Wmean[lane * 2 + 0] + b2 * Wmean[(lane + 64) * 2 + 0];
        float m1 = a * Wmean[lane * 2 + 1] + b2 * Wmean[(lane + 64) * 2 + 1];
        float vv = a * Wv[lane]            + b2 * Wv[lane + 64];
        #pragma unroll
        for (int off = 32; off > 0; off >>= 1) {
            m0 += __shfl_down(m0, off);
            m1 += __shfl_down(m1, off);
            vv += __shfl_down(vv, off);
        }
        if (lane == 0) {
            int row = i0 + r;
            out[row * 2 + 0] = m0 + bmean[0];
            out[row * 2 + 1] = m1 + bmean[1];
            out[3074 + row]  = vv + bv[0];
        }
    }
    if (blockIdx.x == 0 && t < 2) {
        out[3072 + t] = expf(log_std[t]);
    }
}

extern "C" void kernel_launch(void* const* d_in, const int* in_sizes, int n_in,
                              void* d_out, int out_size, void* d_ws, size_t ws_size,
                              hipStream_t stream) {
    const float* x      = (const float*)d_in[0];
    const float* W1     = (const float*)d_in[1];
    const float* b1     = (const float*)d_in[2];
    const float* W2     = (const float*)d_in[3];
    const float* b2     = (const float*)d_in[4];
    const float* Wm     = (const float*)d_in[5];
    const float* bm     = (const float*)d_in[6];
    const float* Wu1    = (const float*)d_in[7];
    const float* bu1    = (const float*)d_in[8];
    const float* Wu2    = (const float*)d_in[9];
    const float* bu2    = (const float*)d_in[10];
    const float* Wmean  = (const float*)d_in[11];
    const float* bmean  = (const float*)d_in[12];
    const float* Wv     = (const float*)d_in[13];
    const float* bv     = (const float*)d_in[14];
    const float* log_std= (const float*)d_in[15];
    float* out = (float*)d_out;

    float* ws = (float*)d_ws;
    float* h  = ws;              // N*64
    float* p  = ws + N * 64;     // N*64

    enc_kernel<<<N / 4, 256, 0, stream>>>(x, W1, b1, W2, b2, Wm, h, p);
    msg_upd_kernel<<<N / RI, 1024, 0, stream>>>(p, bm, h, Wu1, bu1, Wu2, bu2,
                                                Wmean, bmean, Wv, bv, log_std, out);
}

// Round 4
// 22.222 us; speedup vs baseline: 2.6564x; 1.2050x over previous
//
#include <hip/hip_runtime.h>

#define N 1536

// ---------------- K1: node encoder + message projection ----------------
// 256 blocks x 512 threads; 6 rows/block (waves 0..5), float4 weight staging.
__global__ __launch_bounds__(512) void enc_kernel(
    const float* __restrict__ x, const float* __restrict__ W1, const float* __restrict__ b1,
    const float* __restrict__ W2, const float* __restrict__ b2,
    const float* __restrict__ Wm,
    float* __restrict__ h, float* __restrict__ p)
{
    __shared__ float sW2[64 * 64];
    __shared__ float sWm[64 * 64];
    __shared__ float buf1[6][64];
    __shared__ float buf2[6][64];
    int t = threadIdx.x;
    int w = t >> 6, c = t & 63;
    int i0 = blockIdx.x * 6;

    // stage W2, Wm as float4 (1024 float4 each, 512 threads -> 2 each)
    {
        const float4* W2v = (const float4*)W2;
        const float4* Wmv = (const float4*)Wm;
        float4* s2 = (float4*)sW2;
        float4* sm = (float4*)sWm;
        #pragma unroll
        for (int i = t; i < 1024; i += 512) { s2[i] = W2v[i]; sm[i] = Wmv[i]; }
    }

    if (w < 6) {
        int row = i0 + w;
        float4 xv = ((const float4*)x)[row];
        float h1 = xv.x * W1[0 * 64 + c] + xv.y * W1[1 * 64 + c]
                 + xv.z * W1[2 * 64 + c] + xv.w * W1[3 * 64 + c] + b1[c];
        buf1[w][c] = fmaxf(0.f, h1);
    }
    __syncthreads();   // staging + buf1 visible

    if (w < 6) {
        int row = i0 + w;
        float h2 = b2[c];
        #pragma unroll
        for (int k = 0; k < 64; ++k) h2 = fmaf(buf1[w][k], sW2[k * 64 + c], h2);
        h2 = fmaxf(0.f, h2);
        h[row * 64 + c] = h2;
        buf2[w][c] = h2;   // in-wave RAW via lgkmcnt

        float pv = 0.f;
        #pragma unroll
        for (int k = 0; k < 64; ++k) pv = fmaf(buf2[w][k], sWm[k * 64 + c], pv);
        p[row * 64 + c] = pv;
    }
}

// ---------------- K2: fused message pass + update MLP + heads ----------------
// 256 blocks x 1024 threads (16 waves). RI=6 rows per block.
// msgs[i,c] = (1/N)*(sum_j max(p[j,c], q) - N*q), q = p[i,c]-bm[c]
#define RI 6     // rows per block  (256 * 6 = 1536)
#define G  16    // j-groups (one per wave)
#define JPG (N / G)   // 96 j's per group, contiguous chunk
#define JB 8     // load batch depth
__global__ __launch_bounds__(1024) void msg_upd_kernel(
    const float* __restrict__ p, const float* __restrict__ bm,
    const float* __restrict__ h,
    const float* __restrict__ Wu1, const float* __restrict__ bu1,
    const float* __restrict__ Wu2, const float* __restrict__ bu2,
    const float* __restrict__ Wmean, const float* __restrict__ bmean,
    const float* __restrict__ Wv, const float* __restrict__ bv,
    const float* __restrict__ log_std,
    float* __restrict__ out)
{
    __shared__ float red[G][RI][64];     // 24 KB  (j-group partials)
    __shared__ float qs[RI][64];         // 1.5 KB (q values for finalize)
    __shared__ float hu[RI][128];        // 3 KB   ([h, msgs], reused for final u)
    __shared__ float u1s[RI][128];       // 3 KB
    __shared__ float part[8][RI][128];   // 24 KB  (k-split partials)

    int t = threadIdx.x;
    int c = t & 63, g = t >> 6;          // g in 0..15 (wave id)
    int i0 = blockIdx.x * RI;

    // ---- phase A ----
    float bmc = bm[c];
    float q[RI];
    #pragma unroll
    for (int r = 0; r < RI; ++r) q[r] = p[(i0 + r) * 64 + c] - bmc;
    if (g == 0) {
        #pragma unroll
        for (int r = 0; r < RI; ++r) qs[r][c] = q[r];
    }

    const float* pw = p + g * JPG * 64 + c;   // wave-contiguous j chunk
    float acc[RI];
    #pragma unroll
    for (int r = 0; r < RI; ++r) acc[r] = 0.f;

    float pj0[JB], pj1[JB];
    #pragma unroll
    for (int u = 0; u < JB; ++u) pj0[u] = pw[u * 64];

    #pragma unroll
    for (int jj = 0; jj < JPG / JB; ++jj) {
        // prefetch next batch into the other buffer
        if (jj + 1 < JPG / JB) {
            if ((jj & 1) == 0) {
                #pragma unroll
                for (int u = 0; u < JB; ++u) pj1[u] = pw[((jj + 1) * JB + u) * 64];
            } else {
                #pragma unroll
                for (int u = 0; u < JB; ++u) pj0[u] = pw[((jj + 1) * JB + u) * 64];
            }
        }
        if ((jj & 1) == 0) {
            #pragma unroll
            for (int u = 0; u < JB; ++u) {
                #pragma unroll
                for (int r = 0; r < RI; ++r) acc[r] += fmaxf(pj0[u], q[r]);
            }
        } else {
            #pragma unroll
            for (int u = 0; u < JB; ++u) {
                #pragma unroll
                for (int r = 0; r < RI; ++r) acc[r] += fmaxf(pj1[u], q[r]);
            }
        }
    }
    #pragma unroll
    for (int r = 0; r < RI; ++r) red[g][r][c] = acc[r];

    // stage h rows into hu[:, 0:64] (384 entries) with spare waves
    if (t >= 512 && t < 512 + RI * 64) {
        int tt = t - 512;
        hu[tt >> 6][tt & 63] = h[(i0 + (tt >> 6)) * 64 + (tt & 63)];
    }
    __syncthreads();

    // reduce 16 j-group partials, finalize with max-trick correction
    if (t < RI * 64) {
        int r = t >> 6, cc = t & 63;
        float s = 0.f;
        #pragma unroll
        for (int gg = 0; gg < G; ++gg) s += red[gg][r][cc];
        hu[r][64 + cc] = (s - (float)N * qs[r][cc]) * (1.0f / N);
    }
    __syncthreads();

    // ---- phase B: update MLP, k split across 8 groups of 16 ----
    int ch = t & 127, kh = t >> 7;
    {
        float u1[RI];
        #pragma unroll
        for (int r = 0; r < RI; ++r) u1[r] = 0.f;
        #pragma unroll
        for (int k = kh * 16; k < kh * 16 + 16; ++k) {
            float w = Wu1[k * 128 + ch];
            #pragma unroll
            for (int r = 0; r < RI; ++r) u1[r] = fmaf(hu[r][k], w, u1[r]);
        }
        #pragma unroll
        for (int r = 0; r < RI; ++r) part[kh][r][ch] = u1[r];
    }
    __syncthreads();
    if (t < RI * 128) {
        int r = t >> 7, cc = t & 127;
        float v = bu1[cc];
        #pragma unroll
        for (int kk = 0; kk < 8; ++kk) v += part[kk][r][cc];
        u1s[r][cc] = fmaxf(0.f, v);
    }
    __syncthreads();
    {
        float u2[RI];
        #pragma unroll
        for (int r = 0; r < RI; ++r) u2[r] = 0.f;
        #pragma unroll
        for (int k = kh * 16; k < kh * 16 + 16; ++k) {
            float w = Wu2[k * 128 + ch];
            #pragma unroll
            for (int r = 0; r < RI; ++r) u2[r] = fmaf(u1s[r][k], w, u2[r]);
        }
        #pragma unroll
        for (int r = 0; r < RI; ++r) part[kh][r][ch] = u2[r];
    }
    __syncthreads();
    if (t < RI * 128) {
        int r = t >> 7, cc = t & 127;
        float v = bu2[cc];
        #pragma unroll
        for (int kk = 0; kk < 8; ++kk) v += part[kk][r][cc];
        hu[r][cc] = fmaxf(0.f, v);
    }
    __syncthreads();

    // ---- heads: wave g < RI handles row g, 64-lane shuffle reduction ----
    if (g < RI) {
        int r = g, lane = c;
        float a  = hu[r][lane];
        float b2 = hu[r][lane + 64];
        float m0 = a * Wmean[lane * 2 + 0] + b2 * Wmean[(lane + 64) * 2 + 0];
        float m1 = a * Wmean[lane * 2 + 1] + b2 * Wmean[(lane + 64) * 2 + 1];
        float vv = a * Wv[lane]            + b2 * Wv[lane + 64];
        #pragma unroll
        for (int off = 32; off > 0; off >>= 1) {
            m0 += __shfl_down(m0, off);
            m1 += __shfl_down(m1, off);
            vv += __shfl_down(vv, off);
        }
        if (lane == 0) {
            int row = i0 + r;
            out[row * 2 + 0] = m0 + bmean[0];
            out[row * 2 + 1] = m1 + bmean[1];
            out[3074 + row]  = vv + bv[0];
        }
    }
    if (blockIdx.x == 0 && t < 2) {
        out[3072 + t] = expf(log_std[t]);
    }
}

extern "C" void kernel_launch(void* const* d_in, const int* in_sizes, int n_in,
                              void* d_out, int out_size, void* d_ws, size_t ws_size,
                              hipStream_t stream) {
    const float* x      = (const float*)d_in[0];
    const float* W1     = (const float*)d_in[1];
    const float* b1     = (const float*)d_in[2];
    const float* W2     = (const float*)d_in[3];
    const float* b2     = (const float*)d_in[4];
    const float* Wm     = (const float*)d_in[5];
    const float* bm     = (const float*)d_in[6];
    const float* Wu1    = (const float*)d_in[7];
    const float* bu1    = (const float*)d_in[8];
    const float* Wu2    = (const float*)d_in[9];
    const float* bu2    = (const float*)d_in[10];
    const float* Wmean  = (const float*)d_in[11];
    const float* bmean  = (const float*)d_in[12];
    const float* Wv     = (const float*)d_in[13];
    const float* bv     = (const float*)d_in[14];
    const float* log_std= (const float*)d_in[15];
    float* out = (float*)d_out;

    float* ws = (float*)d_ws;
    float* h  = ws;              // N*64
    float* p  = ws + N * 64;     // N*64

    enc_kernel<<<N / 6, 512, 0, stream>>>(x, W1, b1, W2, b2, Wm, h, p);
    msg_upd_kernel<<<N / RI, 1024, 0, stream>>>(p, bm, h, Wu1, bu1, Wu2, bu2,
                                                Wmean, bmean, Wv, bv, log_std, out);
}